// Round 9
// baseline (415.185 us; speedup 1.0000x reference)
//
#include <hip/hip_runtime.h>
#include <hip/hip_bf16.h>

// GCN 3-layer GraphConv, R9 (= R8 + XCD-partitioned sliced aggregation):
//  - hw (GEMM output) stored as 8 column-planes of 16 cols, (N+1) rows each;
//    plane = 3.2MB fits one XCD's 4MB L2
//  - k_aggS: slice s = blockIdx&7 -> pinned to XCD s (round-robin heuristic;
//    correctness independent of mapping); 2 lanes x 16B per node per slice
//  - GEMM: plane-major bf16 A-staging + plane-major output; fp32 feature path
//    (layer 0) unchanged row-major
//  - everything else identical to R8 (padded CSR, fused build, int4 index loads)

constexpr int BLK = 256;
constexpr int CH = 8192;     // edges per partition chunk-block

typedef __attribute__((ext_vector_type(8))) short s8v;
typedef __attribute__((ext_vector_type(4))) float f4v;

__device__ __forceinline__ float bflo(unsigned int u) { return __uint_as_float(u << 16); }
__device__ __forceinline__ float bfhi(unsigned int u) { return __uint_as_float(u & 0xffff0000u); }
__device__ __forceinline__ unsigned int bfr(float f) {
    unsigned int u = __float_as_uint(f);
    return (u + 0x7fffu + ((u >> 16) & 1u)) >> 16;
}
__device__ __forceinline__ unsigned int bfpack(float lo, float hi) {
    unsigned int ul = __float_as_uint(lo), uh = __float_as_uint(hi);
    unsigned int rl = (ul + 0x7fffu + ((ul >> 16) & 1u)) >> 16;
    unsigned int rh = (uh + 0x7fffu + ((uh >> 16) & 1u)) & 0xffff0000u;
    return rl | rh;
}

// ---------------- dual partition count ----------------
__global__ __launch_bounds__(256) void k_pcount(const int* __restrict__ src, const int* __restrict__ dst,
                                                int* __restrict__ pmat_d, int* __restrict__ pmat_s,
                                                int E, int NB) {
    __shared__ int hd[1024], hs[1024];
    for (int i = threadIdx.x; i < 1024; i += 256) { hd[i] = 0; hs[i] = 0; }
    __syncthreads();
    int b = blockIdx.x;
    int e0 = b * CH, e1 = min(e0 + CH, E);
    for (int e = e0 + threadIdx.x; e < e1; e += 256) {
        atomicAdd(&hd[dst[e] >> 7], 1);
        atomicAdd(&hs[src[e] >> 7], 1);
    }
    __syncthreads();
    for (int i = threadIdx.x; i < NB; i += 256) {
        pmat_d[(size_t)b * NB + i] = hd[i];
        pmat_s[(size_t)b * NB + i] = hs[i];
    }
}

// fused scan: bbase + omat + pad-row zeroing (plane-major B2 pads, HW16 pad)
__global__ __launch_bounds__(1024) void k_pscan(const int* __restrict__ pmat_d, const int* __restrict__ pmat_s,
                                                int* __restrict__ bbase_d, int* __restrict__ bbase_s,
                                                int* __restrict__ omat_d, int* __restrict__ omat_s,
                                                unsigned short* __restrict__ B2pad, unsigned short* __restrict__ HW16pad,
                                                int N, int NB, int nblk) {
    const int* pmat = blockIdx.x ? pmat_s : pmat_d;
    int* bbase = blockIdx.x ? bbase_s : bbase_d;
    int* omat  = blockIdx.x ? omat_s : omat_d;
    __shared__ int s[1024];
    int t = threadIdx.x;
    int tot = 0;
    if (t < NB) {
#pragma unroll 8
        for (int b = 0; b < nblk; b++) tot += pmat[(size_t)b * NB + t];
    }
    s[t] = (t < NB) ? tot : 0;
    __syncthreads();
    for (int d = 1; d < 1024; d <<= 1) {
        int x = (t >= d) ? s[t - d] : 0;
        __syncthreads();
        s[t] += x;
        __syncthreads();
    }
    if (t < NB) {
        int base = s[t] - tot;
        bbase[t] = base;
        if (t == NB - 1) bbase[NB] = s[t];
        int run = base;
#pragma unroll 8
        for (int b = 0; b < nblk; b++) {
            size_t idx = (size_t)b * NB + t;
            omat[idx] = run;
            run += pmat[idx];
        }
    }
    if (blockIdx.x == 1) {   // zero pad rows: row N of each of the 8 B2 planes + HW16
        if (t < 128) B2pad[((size_t)(t >> 4) * (N + 1) + N) * 16 + (t & 15)] = 0;
        if (t < 16)  HW16pad[(size_t)N * 16 + t] = 0;
    }
}

__global__ __launch_bounds__(256) void k_pscatter(const int* __restrict__ src, const int* __restrict__ dst,
                                                  const int* __restrict__ omat_d, const int* __restrict__ omat_s,
                                                  unsigned int* __restrict__ ebuf_d, unsigned char* __restrict__ ebuf_s,
                                                  int E, int NB) {
    __shared__ int cd[1024], cs[1024];
    int b = blockIdx.x;
    for (int i = threadIdx.x; i < NB; i += 256) {
        cd[i] = omat_d[(size_t)b * NB + i];
        cs[i] = omat_s[(size_t)b * NB + i];
    }
    __syncthreads();
    int e0 = b * CH, e1 = min(e0 + CH, E);
    for (int e = e0 + threadIdx.x; e < e1; e += 256) {
        int s_ = src[e], d_ = dst[e];
        int pd = atomicAdd(&cd[d_ >> 7], 1);
        ebuf_d[pd] = (unsigned)s_ | ((unsigned)(d_ & 127) << 17);
        int ps = atomicAdd(&cs[s_ >> 7], 1);
        ebuf_s[ps] = (unsigned char)(s_ & 127);
    }
}

// ---------------- fused build: [0,NB) sortcsr (padded) | [NB,2NB) bcount | [2NB,..) wt3 ----------------
__global__ __launch_bounds__(256) void k_build(const unsigned int* __restrict__ ebuf_d,
                                               const int* __restrict__ bbase_d,
                                               const unsigned char* __restrict__ ebuf_s,
                                               const int* __restrict__ bbase_s,
                                               int* __restrict__ csr, int* __restrict__ rowptr,
                                               int* __restrict__ deg, float* __restrict__ srcn,
                                               const float* __restrict__ W0, const float* __restrict__ W1,
                                               const float* __restrict__ W2,
                                               unsigned short* __restrict__ Wt0, unsigned short* __restrict__ Wt1,
                                               unsigned short* __restrict__ Wt2,
                                               int N, int NB) {
    int b = blockIdx.x, tx = threadIdx.x;
    if (b < NB) {
        __shared__ unsigned int rec[3584];
        __shared__ unsigned int sorted[4096];
        __shared__ int cnt[128];
        __shared__ int pws[129];
        __shared__ int wcur[128];
        int k = b;
        int ebeg = bbase_d[k];
        int ecnt = bbase_d[k + 1] - ebeg;
        if (ecnt > 3584) ecnt = 3584;          // Poisson mean ~2046; never triggers
        int pbase = ((ebeg + 3) & ~3) + k * 512;
        if (tx < 128) cnt[tx] = 0;
        __syncthreads();
        for (int i = tx; i < ecnt; i += 256) {
            unsigned int r = ebuf_d[ebeg + i];
            rec[i] = r;
            atomicAdd(&cnt[(r >> 17) & 127], 1);
        }
        __syncthreads();
        int pc = (tx < 128) ? ((cnt[tx] + 3) & ~3) : 0;
        if (tx < 128) wcur[tx] = pc;
        __syncthreads();
        for (int d = 1; d < 128; d <<= 1) {
            int x = (tx < 128 && tx >= d) ? wcur[tx - d] : 0;
            __syncthreads();
            if (tx < 128) wcur[tx] += x;
            __syncthreads();
        }
        if (tx < 128) pws[tx] = wcur[tx] - pc;
        if (tx == 127) pws[128] = wcur[127];
        __syncthreads();
        int pecnt = pws[128];
        for (int i = tx; i < pecnt; i += 256) sorted[i] = (unsigned)N;  // pad value
        if (tx < 128) wcur[tx] = pws[tx];
        __syncthreads();
        for (int i = tx; i < ecnt; i += 256) {
            unsigned int r = rec[i];
            int p = atomicAdd(&wcur[(r >> 17) & 127], 1);
            sorted[p] = r & 0x1FFFFu;
        }
        __syncthreads();
        for (int i = tx; i < pecnt; i += 256) csr[pbase + i] = (int)sorted[i];
        if (tx < 128) {
            int v = k * 128 + tx;
            if (v < N) { rowptr[v] = pbase + pws[tx]; deg[v] = cnt[tx]; }
        }
    } else if (b < 2 * NB) {
        __shared__ int scnt[128];
        int k = b - NB;
        if (tx < 128) scnt[tx] = 0;
        __syncthreads();
        int beg = bbase_s[k], end = bbase_s[k + 1];
        for (int i = beg + tx; i < end; i += 256) atomicAdd(&scnt[ebuf_s[i]], 1);
        __syncthreads();
        if (tx < 128) {
            int v = k * 128 + tx;
            if (v < N) {
                int c = scnt[tx];
                if (c < 1) c = 1;
                srcn[v] = rsqrtf((float)c);
            }
        }
    } else {
        int bb = b - 2 * NB;
        const float* W; unsigned short* Wt; int total, base;
        if (bb < 64)      { W = W0; Wt = Wt0; total = 16384; base = bb * 256; }
        else if (bb < 128){ W = W1; Wt = Wt1; total = 16384; base = (bb - 64) * 256; }
        else              { W = W2; Wt = Wt2; total = 2048;  base = (bb - 128) * 256; }
        int i = base + tx;
        if (i < total) {
            int Ncol = total >> 7;
            int c = i >> 7, kk = i & 127;
            Wt[i] = (unsigned short)bfr(W[kk * Ncol + c]);
        }
    }
}

// ---------------- MFMA GEMM: 256 rows/block, Ws once, plane-major bf16 A + plane-major out ----------------
// bf16 input layout: plane pl (16 cols) x (M+1) rows x 16 ushorts. fp32 path (F32IN) row-major.
template <int NT, int F32IN>
__global__ __launch_bounds__(256) void k_gemm_mfma(const unsigned short* __restrict__ Ab,
                                                   const float* __restrict__ Af,
                                                   const float* __restrict__ srcn,
                                                   const unsigned short* __restrict__ Wt,
                                                   unsigned short* __restrict__ outb, int M) {
    __shared__ unsigned short Ws[NT * 16 * 128];
    __shared__ unsigned short As[64 * 128];
    int tx = threadIdx.x;
    for (int p = 0; p < NT; ++p) {
        int r = p * 16 + (tx >> 4);
        int c = tx & 15;
        int cs = c ^ (r & 7);
        *(uint4*)(&Ws[(r * 16 + cs) * 8]) = *(const uint4*)(Wt + (size_t)r * 128 + c * 8);
    }
    int w = tx >> 6, l = tx & 63;
    int lr = l & 15, lg = l >> 4;
    int ar = w * 16 + lr;

    for (int strip = 0; strip < 4; ++strip) {
        int row0 = blockIdx.x * 256 + strip * 64;
        __syncthreads();   // Ws ready (1st iter) / prior As reads complete
        if (F32IN) {
            for (int p = 0; p < 4; ++p) {
                int r = p * 16 + (tx >> 4);
                int c = tx & 15;
                int cs = c ^ (r & 7);
                int gr = row0 + r;
                uint4 v = make_uint4(0u, 0u, 0u, 0u);
                if (gr < M) {
                    const float4* pf = (const float4*)(Af + (size_t)gr * 128 + c * 8);
                    float4 a = pf[0], bq = pf[1];
                    float s = srcn[gr];
                    v.x = bfpack(a.x * s, a.y * s);
                    v.y = bfpack(a.z * s, a.w * s);
                    v.z = bfpack(bq.x * s, bq.y * s);
                    v.w = bfpack(bq.z * s, bq.w * s);
                }
                *(uint4*)(&As[(r * 16 + cs) * 8]) = v;
            }
        } else {
            // plane-major: 1024 chunks of 8 ushorts; f -> (plane, row, half)
            for (int lq = 0; lq < 4; ++lq) {
                int f = tx + lq * 256;
                int pl = f >> 7;
                int j = f & 127;
                int r = j >> 1, hf = j & 1;
                int gr = row0 + r;
                uint4 v = make_uint4(0u, 0u, 0u, 0u);
                if (gr < M) v = *(const uint4*)(Ab + ((size_t)pl * (M + 1) + gr) * 16 + hf * 8);
                int c = pl * 2 + hf;
                *(uint4*)(&As[(r * 16 + (c ^ (r & 7))) * 8]) = v;
            }
        }
        __syncthreads();

        f4v acc[NT];
#pragma unroll
        for (int nt = 0; nt < NT; ++nt) { acc[nt][0] = 0.f; acc[nt][1] = 0.f; acc[nt][2] = 0.f; acc[nt][3] = 0.f; }
#pragma unroll
        for (int kk = 0; kk < 4; ++kk) {
            s8v af = *(const s8v*)(&As[(ar * 16 + ((kk * 4 + lg) ^ (ar & 7))) * 8]);
#pragma unroll
            for (int nt = 0; nt < NT; ++nt) {
                int br = nt * 16 + lr;
                s8v bf = *(const s8v*)(&Ws[(br * 16 + ((kk * 4 + lg) ^ (br & 7))) * 8]);
                acc[nt] = __builtin_amdgcn_mfma_f32_16x16x32_bf16(af, bf, acc[nt], 0, 0, 0);
            }
        }
        // plane-major store: plane nt, row R, col-in-plane lr (NT=1 -> row-major N x 16)
#pragma unroll
        for (int nt = 0; nt < NT; ++nt) {
#pragma unroll
            for (int i = 0; i < 4; ++i) {
                int R = row0 + w * 16 + lg * 4 + i;
                if (R < M) {
                    outb[((size_t)nt * (M + 1) + R) * 16 + lr] = (unsigned short)bfr(acc[nt][i]);
                }
            }
        }
    }
}

// ---------------- agg 128-wide, sliced: slice s = blockIdx&7 (XCD-pinned), 2 lanes/node ----------------
// gathers 32B slice-rows from plane s; writes plane-major out (B1)
__global__ __launch_bounds__(256) void k_aggS(const unsigned short* __restrict__ hw,
                                              const int* __restrict__ csr,
                                              const int* __restrict__ rowptr,
                                              const int* __restrict__ deg,
                                              const float* __restrict__ srcn,
                                              const float* __restrict__ bias,
                                              unsigned short* __restrict__ out, int N) {
    int s = blockIdx.x & 7;
    int r = blockIdx.x >> 3;
    int idx = r * 256 + threadIdx.x;
    int v = idx >> 1, half = idx & 1;
    if (v >= N) return;
    int s0 = rowptr[v];
    int dg = deg[v];
    int plen = (dg + 3) & ~3;
    const unsigned short* hws = hw + (size_t)s * (N + 1) * 16 + half * 8;

    float a0 = 0.f, a1 = 0.f, a2 = 0.f, a3 = 0.f, a4 = 0.f, a5 = 0.f, a6 = 0.f, a7 = 0.f;
#define ACC8(V)                                                         \
    a0 += bflo(V.x); a1 += bfhi(V.x); a2 += bflo(V.y); a3 += bfhi(V.y); \
    a4 += bflo(V.z); a5 += bfhi(V.z); a6 += bflo(V.w); a7 += bfhi(V.w);
    for (int e = s0; e < s0 + plen; e += 4) {
        int4 xs = *(const int4*)(csr + e);      // both half-lanes read same line (broadcast)
        uint4 v0 = *(const uint4*)(hws + (size_t)xs.x * 16);
        uint4 v1 = *(const uint4*)(hws + (size_t)xs.y * 16);
        uint4 v2 = *(const uint4*)(hws + (size_t)xs.z * 16);
        uint4 v3 = *(const uint4*)(hws + (size_t)xs.w * 16);
        ACC8(v0) ACC8(v1) ACC8(v2) ACC8(v3)
    }
#undef ACC8
    int d = dg < 1 ? 1 : dg;
    float dn = rsqrtf((float)d);
    int col = s * 16 + half * 8;
    float4 b0 = *(const float4*)(bias + col);
    float4 b1 = *(const float4*)(bias + col + 4);
    float sn = srcn[v];
    float o0 = fmaxf(a0 * dn + b0.x, 0.f) * sn, o1 = fmaxf(a1 * dn + b0.y, 0.f) * sn;
    float o2 = fmaxf(a2 * dn + b0.z, 0.f) * sn, o3 = fmaxf(a3 * dn + b0.w, 0.f) * sn;
    float o4 = fmaxf(a4 * dn + b1.x, 0.f) * sn, o5 = fmaxf(a5 * dn + b1.y, 0.f) * sn;
    float o6 = fmaxf(a6 * dn + b1.z, 0.f) * sn, o7 = fmaxf(a7 * dn + b1.w, 0.f) * sn;
    uint4 o;
    o.x = bfpack(o0, o1); o.y = bfpack(o2, o3);
    o.z = bfpack(o4, o5); o.w = bfpack(o6, o7);
    // plane-major write: plane s, row v, half*8 (coalesced: 32B/pair, contiguous)
    *(uint4*)(out + ((size_t)s * (N + 1) + v) * 16 + half * 8) = o;
}

// ---------------- agg 16-wide (layer 2): 4-lane/node, int4 indices, bias+sigmoid ----------------
__global__ __launch_bounds__(256) void k_agg16(const unsigned short* __restrict__ hw,
                                               const int* __restrict__ csr,
                                               const int* __restrict__ rowptr,
                                               const int* __restrict__ deg,
                                               const float* __restrict__ bias,
                                               float* __restrict__ out, int N) {
    int t = blockIdx.x * 256 + threadIdx.x;
    int v = t >> 2, q = t & 3;
    if (v >= N) return;
    int s0 = rowptr[v];
    int dg = deg[v];
    int plen = (dg + 3) & ~3;
    const unsigned short* hws = hw + q * 4;
    float a0 = 0.f, a1 = 0.f, a2 = 0.f, a3 = 0.f;
#define ACC4(V)                                                         \
    a0 += bflo(V.x); a1 += bfhi(V.x); a2 += bflo(V.y); a3 += bfhi(V.y);
    for (int e = s0; e < s0 + plen; e += 4) {
        int4 xs = *(const int4*)(csr + e);
        uint2 v0 = *(const uint2*)(hws + (size_t)xs.x * 16);
        uint2 v1 = *(const uint2*)(hws + (size_t)xs.y * 16);
        uint2 v2 = *(const uint2*)(hws + (size_t)xs.z * 16);
        uint2 v3 = *(const uint2*)(hws + (size_t)xs.w * 16);
        ACC4(v0) ACC4(v1) ACC4(v2) ACC4(v3)
    }
#undef ACC4
    int d = dg < 1 ? 1 : dg;
    float dn = rsqrtf((float)d);
    float4 b = *(const float4*)(bias + q * 4);
    float o0 = 1.f / (1.f + __expf(-(a0 * dn + b.x))) + 1e-8f;
    float o1 = 1.f / (1.f + __expf(-(a1 * dn + b.y))) + 1e-8f;
    float o2 = 1.f / (1.f + __expf(-(a2 * dn + b.z))) + 1e-8f;
    float o3 = 1.f / (1.f + __expf(-(a3 * dn + b.w))) + 1e-8f;
    *(float4*)(out + (size_t)v * 16 + q * 4) = make_float4(o0, o1, o2, o3);
}

extern "C" void kernel_launch(void* const* d_in, const int* in_sizes, int n_in,
                              void* d_out, int out_size, void* d_ws, size_t ws_size,
                              hipStream_t stream) {
    const float* features = (const float*)d_in[0];
    const int*   src      = (const int*)d_in[1];
    const int*   dst      = (const int*)d_in[2];
    const float* W0       = (const float*)d_in[3];
    const float* b0       = (const float*)d_in[4];
    const float* W1       = (const float*)d_in[5];
    const float* b1       = (const float*)d_in[6];
    const float* W2       = (const float*)d_in[7];
    const float* b2       = (const float*)d_in[8];
    float* out = (float*)d_out;

    const int N = in_sizes[0] / 128;
    const int E = in_sizes[1];
    const int NB = (N + 127) >> 7;            // 782 buckets
    const int nblk = (E + CH - 1) / CH;       // 196 partition chunks

    char* ws = (char*)d_ws;
    size_t off = 0;
    auto alloc = [&](size_t bytes) -> char* {
        char* p = ws + off;
        off += (bytes + 255) / 256 * 256;
        return p;
    };
    int* pmat_d  = (int*)alloc((size_t)nblk * NB * 4);
    int* pmat_s  = (int*)alloc((size_t)nblk * NB * 4);
    int* omat_d  = (int*)alloc((size_t)nblk * NB * 4);
    int* omat_s  = (int*)alloc((size_t)nblk * NB * 4);
    int* bbase_d = (int*)alloc((size_t)(NB + 1) * 4);
    int* bbase_s = (int*)alloc((size_t)(NB + 1) * 4);
    unsigned int*  ebuf_d = (unsigned int*)alloc((size_t)E * 4);
    unsigned char* ebuf_s = (unsigned char*)alloc((size_t)E);
    int* csr     = (int*)alloc(((size_t)E + (size_t)NB * 512 + 512) * 4);   // padded CSR
    int* rowptr  = (int*)alloc((size_t)(N + 1) * 4);
    int* deg     = (int*)alloc((size_t)N * 4);
    float* srcn  = (float*)alloc((size_t)N * 4);
    unsigned short* Wt0 = (unsigned short*)alloc(128 * 128 * 2);
    unsigned short* Wt1 = (unsigned short*)alloc(128 * 128 * 2);
    unsigned short* Wt2 = (unsigned short*)alloc(16 * 128 * 2);
    unsigned short* B1 = (unsigned short*)alloc((size_t)(N + 1) * 128 * 2);  // plane-major, +1 pad row/plane
    unsigned short* B2 = (unsigned short*)alloc((size_t)(N + 1) * 128 * 2);  // plane-major, +1 pad row/plane
    unsigned short* HW16 = (unsigned short*)alloc((size_t)(N + 1) * 16 * 2); // +1 zero pad row
    (void)ws_size; (void)n_in; (void)out_size;

    // graph build (no global data atomics)
    k_pcount<<<nblk, 256, 0, stream>>>(src, dst, pmat_d, pmat_s, E, NB);
    k_pscan<<<2, 1024, 0, stream>>>(pmat_d, pmat_s, bbase_d, bbase_s, omat_d, omat_s, B2, HW16, N, NB, nblk);
    k_pscatter<<<nblk, 256, 0, stream>>>(src, dst, omat_d, omat_s, ebuf_d, ebuf_s, E, NB);
    k_build<<<2 * NB + 136, 256, 0, stream>>>(ebuf_d, bbase_d, ebuf_s, bbase_s, csr, rowptr, deg, srcn,
                                              W0, W1, W2, Wt0, Wt1, Wt2, N, NB);

    int gb = (N + 255) / 256;                     // 391 GEMM blocks
    int bps = (2 * N + 255) / 256;                // 782 blocks per slice
    int asb = bps * 8;                            // sliced agg grid
    int a16b = (N * 4 + 255) / 256;

    // layer 0 (fp32 features, scaled by srcn during staging) -> B2 planes
    k_gemm_mfma<8, 1><<<gb, 256, 0, stream>>>(nullptr, features, srcn, Wt0, B2, N);
    k_aggS<<<asb, 256, 0, stream>>>(B2, csr, rowptr, deg, srcn, b0, B1, N);
    // layer 1: B1 planes -> B2 planes -> B1 planes
    k_gemm_mfma<8, 0><<<gb, 256, 0, stream>>>(B1, nullptr, nullptr, Wt1, B2, N);
    k_aggS<<<asb, 256, 0, stream>>>(B2, csr, rowptr, deg, srcn, b1, B1, N);
    // layer 2: GEMM to 16-wide (plane0 = row-major), then 32B-row gather w/ bias+sigmoid
    k_gemm_mfma<1, 0><<<gb, 256, 0, stream>>>(B1, nullptr, nullptr, Wt2, HW16, N);
    k_agg16<<<a16b, 256, 0, stream>>>(HW16, csr, rowptr, deg, b2, out, N);
}

// Round 10
// 357.530 us; speedup vs baseline: 1.1613x; 1.1613x over previous
//
#include <hip/hip_runtime.h>
#include <hip/hip_bf16.h>

// GCN 3-layer GraphConv, R10 (= R8 base; R9 slicing reverted):
//  - GEMM v2: register-resident B (32 frags = 128 VGPR), direct-global A frags,
//    LDS-free, barrier-free, software-pipelined strips, launch_bounds(256,2)
//  - aggN: 8-edge unroll (2x int4 idx + 8 row loads in flight)
//  - build chain / padded CSR / fused kernels identical to R8 (verified)

constexpr int BLK = 256;
constexpr int CH = 8192;     // edges per partition chunk-block

typedef __attribute__((ext_vector_type(8))) short s8v;
typedef __attribute__((ext_vector_type(4))) float f4v;

__device__ __forceinline__ float bflo(unsigned int u) { return __uint_as_float(u << 16); }
__device__ __forceinline__ float bfhi(unsigned int u) { return __uint_as_float(u & 0xffff0000u); }
__device__ __forceinline__ unsigned int bfr(float f) {
    unsigned int u = __float_as_uint(f);
    return (u + 0x7fffu + ((u >> 16) & 1u)) >> 16;
}
__device__ __forceinline__ unsigned int bfpack(float lo, float hi) {
    unsigned int ul = __float_as_uint(lo), uh = __float_as_uint(hi);
    unsigned int rl = (ul + 0x7fffu + ((ul >> 16) & 1u)) >> 16;
    unsigned int rh = (uh + 0x7fffu + ((uh >> 16) & 1u)) & 0xffff0000u;
    return rl | rh;
}

// ---------------- dual partition count ----------------
__global__ __launch_bounds__(256) void k_pcount(const int* __restrict__ src, const int* __restrict__ dst,
                                                int* __restrict__ pmat_d, int* __restrict__ pmat_s,
                                                int E, int NB) {
    __shared__ int hd[1024], hs[1024];
    for (int i = threadIdx.x; i < 1024; i += 256) { hd[i] = 0; hs[i] = 0; }
    __syncthreads();
    int b = blockIdx.x;
    int e0 = b * CH, e1 = min(e0 + CH, E);
    for (int e = e0 + threadIdx.x; e < e1; e += 256) {
        atomicAdd(&hd[dst[e] >> 7], 1);
        atomicAdd(&hs[src[e] >> 7], 1);
    }
    __syncthreads();
    for (int i = threadIdx.x; i < NB; i += 256) {
        pmat_d[(size_t)b * NB + i] = hd[i];
        pmat_s[(size_t)b * NB + i] = hs[i];
    }
}

// fused scan: bbase + omat + pad-row zeroing
__global__ __launch_bounds__(1024) void k_pscan(const int* __restrict__ pmat_d, const int* __restrict__ pmat_s,
                                                int* __restrict__ bbase_d, int* __restrict__ bbase_s,
                                                int* __restrict__ omat_d, int* __restrict__ omat_s,
                                                unsigned short* __restrict__ B2pad, unsigned short* __restrict__ HW16pad,
                                                int N, int NB, int nblk) {
    const int* pmat = blockIdx.x ? pmat_s : pmat_d;
    int* bbase = blockIdx.x ? bbase_s : bbase_d;
    int* omat  = blockIdx.x ? omat_s : omat_d;
    __shared__ int s[1024];
    int t = threadIdx.x;
    int tot = 0;
    if (t < NB) {
#pragma unroll 8
        for (int b = 0; b < nblk; b++) tot += pmat[(size_t)b * NB + t];
    }
    s[t] = (t < NB) ? tot : 0;
    __syncthreads();
    for (int d = 1; d < 1024; d <<= 1) {
        int x = (t >= d) ? s[t - d] : 0;
        __syncthreads();
        s[t] += x;
        __syncthreads();
    }
    if (t < NB) {
        int base = s[t] - tot;
        bbase[t] = base;
        if (t == NB - 1) bbase[NB] = s[t];
        int run = base;
#pragma unroll 8
        for (int b = 0; b < nblk; b++) {
            size_t idx = (size_t)b * NB + t;
            omat[idx] = run;
            run += pmat[idx];
        }
    }
    if (blockIdx.x == 1) {   // zero the pad rows (row N) read by agg kernels
        if (t < 128) B2pad[(size_t)N * 128 + t] = 0;
        if (t < 16)  HW16pad[(size_t)N * 16 + t] = 0;
    }
}

__global__ __launch_bounds__(256) void k_pscatter(const int* __restrict__ src, const int* __restrict__ dst,
                                                  const int* __restrict__ omat_d, const int* __restrict__ omat_s,
                                                  unsigned int* __restrict__ ebuf_d, unsigned char* __restrict__ ebuf_s,
                                                  int E, int NB) {
    __shared__ int cd[1024], cs[1024];
    int b = blockIdx.x;
    for (int i = threadIdx.x; i < NB; i += 256) {
        cd[i] = omat_d[(size_t)b * NB + i];
        cs[i] = omat_s[(size_t)b * NB + i];
    }
    __syncthreads();
    int e0 = b * CH, e1 = min(e0 + CH, E);
    for (int e = e0 + threadIdx.x; e < e1; e += 256) {
        int s_ = src[e], d_ = dst[e];
        int pd = atomicAdd(&cd[d_ >> 7], 1);
        ebuf_d[pd] = (unsigned)s_ | ((unsigned)(d_ & 127) << 17);
        int ps = atomicAdd(&cs[s_ >> 7], 1);
        ebuf_s[ps] = (unsigned char)(s_ & 127);
    }
}

// ---------------- fused build: [0,NB) sortcsr (padded) | [NB,2NB) bcount | [2NB,..) wt3 ----------------
__global__ __launch_bounds__(256) void k_build(const unsigned int* __restrict__ ebuf_d,
                                               const int* __restrict__ bbase_d,
                                               const unsigned char* __restrict__ ebuf_s,
                                               const int* __restrict__ bbase_s,
                                               int* __restrict__ csr, int* __restrict__ rowptr,
                                               int* __restrict__ deg, float* __restrict__ srcn,
                                               const float* __restrict__ W0, const float* __restrict__ W1,
                                               const float* __restrict__ W2,
                                               unsigned short* __restrict__ Wt0, unsigned short* __restrict__ Wt1,
                                               unsigned short* __restrict__ Wt2,
                                               int N, int NB) {
    int b = blockIdx.x, tx = threadIdx.x;
    if (b < NB) {
        __shared__ unsigned int rec[3584];
        __shared__ unsigned int sorted[4096];
        __shared__ int cnt[128];
        __shared__ int pws[129];
        __shared__ int wcur[128];
        int k = b;
        int ebeg = bbase_d[k];
        int ecnt = bbase_d[k + 1] - ebeg;
        if (ecnt > 3584) ecnt = 3584;          // Poisson mean ~2046; never triggers
        int pbase = ((ebeg + 3) & ~3) + k * 512;
        if (tx < 128) cnt[tx] = 0;
        __syncthreads();
        for (int i = tx; i < ecnt; i += 256) {
            unsigned int r = ebuf_d[ebeg + i];
            rec[i] = r;
            atomicAdd(&cnt[(r >> 17) & 127], 1);
        }
        __syncthreads();
        int pc = (tx < 128) ? ((cnt[tx] + 3) & ~3) : 0;
        if (tx < 128) wcur[tx] = pc;
        __syncthreads();
        for (int d = 1; d < 128; d <<= 1) {
            int x = (tx < 128 && tx >= d) ? wcur[tx - d] : 0;
            __syncthreads();
            if (tx < 128) wcur[tx] += x;
            __syncthreads();
        }
        if (tx < 128) pws[tx] = wcur[tx] - pc;
        if (tx == 127) pws[128] = wcur[127];
        __syncthreads();
        int pecnt = pws[128];
        for (int i = tx; i < pecnt; i += 256) sorted[i] = (unsigned)N;  // pad value
        if (tx < 128) wcur[tx] = pws[tx];
        __syncthreads();
        for (int i = tx; i < ecnt; i += 256) {
            unsigned int r = rec[i];
            int p = atomicAdd(&wcur[(r >> 17) & 127], 1);
            sorted[p] = r & 0x1FFFFu;
        }
        __syncthreads();
        for (int i = tx; i < pecnt; i += 256) csr[pbase + i] = (int)sorted[i];
        if (tx < 128) {
            int v = k * 128 + tx;
            if (v < N) { rowptr[v] = pbase + pws[tx]; deg[v] = cnt[tx]; }
        }
    } else if (b < 2 * NB) {
        __shared__ int scnt[128];
        int k = b - NB;
        if (tx < 128) scnt[tx] = 0;
        __syncthreads();
        int beg = bbase_s[k], end = bbase_s[k + 1];
        for (int i = beg + tx; i < end; i += 256) atomicAdd(&scnt[ebuf_s[i]], 1);
        __syncthreads();
        if (tx < 128) {
            int v = k * 128 + tx;
            if (v < N) {
                int c = scnt[tx];
                if (c < 1) c = 1;
                srcn[v] = rsqrtf((float)c);
            }
        }
    } else {
        int bb = b - 2 * NB;
        const float* W; unsigned short* Wt; int total, base;
        if (bb < 64)      { W = W0; Wt = Wt0; total = 16384; base = bb * 256; }
        else if (bb < 128){ W = W1; Wt = Wt1; total = 16384; base = (bb - 64) * 256; }
        else              { W = W2; Wt = Wt2; total = 2048;  base = (bb - 128) * 256; }
        int i = base + tx;
        if (i < total) {
            int Ncol = total >> 7;
            int c = i >> 7, kk = i & 127;
            Wt[i] = (unsigned short)bfr(W[kk * Ncol + c]);
        }
    }
}

// ---------------- MFMA GEMM v2: register-B, direct-global A, no LDS, no barriers ----------------
// wave owns 64 rows (4 strips of 16); B frags loaded once per wave (L2 broadcast).
template <int NT, int F32IN>
__global__ __launch_bounds__(256, 2) void k_gemm_mfma(const unsigned short* __restrict__ Ab,
                                                      const float* __restrict__ Af,
                                                      const float* __restrict__ srcn,
                                                      const unsigned short* __restrict__ Wt,
                                                      unsigned short* __restrict__ outb, int M) {
    int tx = threadIdx.x;
    int w = tx >> 6, l = tx & 63;
    int lr = l & 15, lg = l >> 4;
    int wbase = (blockIdx.x * 4 + w) * 64;

    s8v bf[NT][4];
#pragma unroll
    for (int nt = 0; nt < NT; ++nt) {
        int br = nt * 16 + lr;
#pragma unroll
        for (int kk = 0; kk < 4; ++kk)
            bf[nt][kk] = *(const s8v*)(Wt + (size_t)br * 128 + (kk * 4 + lg) * 8);
    }

    union U { uint4 u; s8v v; };
    U bufA[4], bufB[4];

#define LOADA(S, DST)                                                          \
    {                                                                          \
        int r0_ = wbase + (S) * 16 + lr;                                       \
        if (r0_ < M) {                                                         \
            if (F32IN) {                                                       \
                float sn_ = srcn[r0_];                                         \
                _Pragma("unroll")                                              \
                for (int kk = 0; kk < 4; ++kk) {                               \
                    const float4* pf = (const float4*)(Af + (size_t)r0_ * 128 + (kk * 4 + lg) * 8); \
                    float4 x = pf[0], y = pf[1];                               \
                    DST[kk].u.x = bfpack(x.x * sn_, x.y * sn_);                \
                    DST[kk].u.y = bfpack(x.z * sn_, x.w * sn_);                \
                    DST[kk].u.z = bfpack(y.x * sn_, y.y * sn_);                \
                    DST[kk].u.w = bfpack(y.z * sn_, y.w * sn_);                \
                }                                                              \
            } else {                                                           \
                _Pragma("unroll")                                              \
                for (int kk = 0; kk < 4; ++kk)                                 \
                    DST[kk].u = *(const uint4*)(Ab + (size_t)r0_ * 128 + (kk * 4 + lg) * 8); \
            }                                                                  \
        } else {                                                               \
            _Pragma("unroll")                                                  \
            for (int kk = 0; kk < 4; ++kk) DST[kk].u = make_uint4(0u, 0u, 0u, 0u); \
        }                                                                      \
    }

#define COMPUTE(S, CUR)                                                        \
    {                                                                          \
        f4v acc[NT];                                                           \
        _Pragma("unroll")                                                      \
        for (int nt = 0; nt < NT; ++nt) { acc[nt][0] = 0.f; acc[nt][1] = 0.f; acc[nt][2] = 0.f; acc[nt][3] = 0.f; } \
        _Pragma("unroll")                                                      \
        for (int kk = 0; kk < 4; ++kk) {                                       \
            _Pragma("unroll")                                                  \
            for (int nt = 0; nt < NT; ++nt)                                    \
                acc[nt] = __builtin_amdgcn_mfma_f32_16x16x32_bf16(CUR[kk].v, bf[nt][kk], acc[nt], 0, 0, 0); \
        }                                                                      \
        _Pragma("unroll")                                                      \
        for (int nt = 0; nt < NT; ++nt) {                                      \
            _Pragma("unroll")                                                  \
            for (int i = 0; i < 4; ++i) {                                      \
                int R = wbase + (S) * 16 + lg * 4 + i;                         \
                if (R < M) outb[(size_t)R * (NT * 16) + nt * 16 + lr] = (unsigned short)bfr(acc[nt][i]); \
            }                                                                  \
        }                                                                      \
    }

    LOADA(0, bufA)
    LOADA(1, bufB)
    COMPUTE(0, bufA)
    LOADA(2, bufA)
    COMPUTE(1, bufB)
    LOADA(3, bufB)
    COMPUTE(2, bufA)
    COMPUTE(3, bufB)
#undef LOADA
#undef COMPUTE
}

// ---------------- agg 128-wide: 16-lane/node, 8-edge unroll over padded CSR ----------------
__global__ __launch_bounds__(256) void k_aggN(const unsigned short* __restrict__ hw,
                                              const int* __restrict__ csr,
                                              const int* __restrict__ rowptr,
                                              const int* __restrict__ deg,
                                              const float* __restrict__ srcn,
                                              const float* __restrict__ bias,
                                              unsigned short* __restrict__ out, int N) {
    int t = blockIdx.x * 256 + threadIdx.x;
    int v = t >> 4, sub = t & 15;
    if (v >= N) return;
    int s0 = rowptr[v];
    int dg = deg[v];
    int plen = (dg + 3) & ~3;
    const unsigned short* hws = hw + sub * 8;

    float a0 = 0.f, a1 = 0.f, a2 = 0.f, a3 = 0.f, a4 = 0.f, a5 = 0.f, a6 = 0.f, a7 = 0.f;
#define ACC8(V)                                                         \
    a0 += bflo(V.x); a1 += bfhi(V.x); a2 += bflo(V.y); a3 += bfhi(V.y); \
    a4 += bflo(V.z); a5 += bfhi(V.z); a6 += bflo(V.w); a7 += bfhi(V.w);
    int e = s0;
    int end8 = s0 + (plen & ~7);
    for (; e < end8; e += 8) {       // 8 rows + 2 idx loads in flight
        int4 xa = *(const int4*)(csr + e);
        int4 xb = *(const int4*)(csr + e + 4);
        uint4 v0 = *(const uint4*)(hws + (size_t)xa.x * 128);
        uint4 v1 = *(const uint4*)(hws + (size_t)xa.y * 128);
        uint4 v2 = *(const uint4*)(hws + (size_t)xa.z * 128);
        uint4 v3 = *(const uint4*)(hws + (size_t)xa.w * 128);
        uint4 v4 = *(const uint4*)(hws + (size_t)xb.x * 128);
        uint4 v5 = *(const uint4*)(hws + (size_t)xb.y * 128);
        uint4 v6 = *(const uint4*)(hws + (size_t)xb.z * 128);
        uint4 v7 = *(const uint4*)(hws + (size_t)xb.w * 128);
        ACC8(v0) ACC8(v1) ACC8(v2) ACC8(v3) ACC8(v4) ACC8(v5) ACC8(v6) ACC8(v7)
    }
    if (plen & 4) {
        int4 xs = *(const int4*)(csr + e);
        uint4 v0 = *(const uint4*)(hws + (size_t)xs.x * 128);
        uint4 v1 = *(const uint4*)(hws + (size_t)xs.y * 128);
        uint4 v2 = *(const uint4*)(hws + (size_t)xs.z * 128);
        uint4 v3 = *(const uint4*)(hws + (size_t)xs.w * 128);
        ACC8(v0) ACC8(v1) ACC8(v2) ACC8(v3)
    }
#undef ACC8
    int d = dg < 1 ? 1 : dg;
    float dn = rsqrtf((float)d);
    float4 b0 = *(const float4*)(bias + sub * 8);
    float4 b1 = *(const float4*)(bias + sub * 8 + 4);
    float sn = srcn[v];
    float o0 = fmaxf(a0 * dn + b0.x, 0.f) * sn, o1 = fmaxf(a1 * dn + b0.y, 0.f) * sn;
    float o2 = fmaxf(a2 * dn + b0.z, 0.f) * sn, o3 = fmaxf(a3 * dn + b0.w, 0.f) * sn;
    float o4 = fmaxf(a4 * dn + b1.x, 0.f) * sn, o5 = fmaxf(a5 * dn + b1.y, 0.f) * sn;
    float o6 = fmaxf(a6 * dn + b1.z, 0.f) * sn, o7 = fmaxf(a7 * dn + b1.w, 0.f) * sn;
    uint4 o;
    o.x = bfpack(o0, o1); o.y = bfpack(o2, o3);
    o.z = bfpack(o4, o5); o.w = bfpack(o6, o7);
    *(uint4*)(out + (size_t)v * 128 + sub * 8) = o;
}

// ---------------- agg 16-wide (layer 2): 4-lane/node, int4 indices, bias+sigmoid ----------------
__global__ __launch_bounds__(256) void k_agg16(const unsigned short* __restrict__ hw,
                                               const int* __restrict__ csr,
                                               const int* __restrict__ rowptr,
                                               const int* __restrict__ deg,
                                               const float* __restrict__ bias,
                                               float* __restrict__ out, int N) {
    int t = blockIdx.x * 256 + threadIdx.x;
    int v = t >> 2, q = t & 3;
    if (v >= N) return;
    int s0 = rowptr[v];
    int dg = deg[v];
    int plen = (dg + 3) & ~3;
    const unsigned short* hws = hw + q * 4;
    float a0 = 0.f, a1 = 0.f, a2 = 0.f, a3 = 0.f;
#define ACC4(V)                                                         \
    a0 += bflo(V.x); a1 += bfhi(V.x); a2 += bflo(V.y); a3 += bfhi(V.y);
    for (int e = s0; e < s0 + plen; e += 4) {
        int4 xs = *(const int4*)(csr + e);
        uint2 v0 = *(const uint2*)(hws + (size_t)xs.x * 16);
        uint2 v1 = *(const uint2*)(hws + (size_t)xs.y * 16);
        uint2 v2 = *(const uint2*)(hws + (size_t)xs.z * 16);
        uint2 v3 = *(const uint2*)(hws + (size_t)xs.w * 16);
        ACC4(v0) ACC4(v1) ACC4(v2) ACC4(v3)
    }
#undef ACC4
    int d = dg < 1 ? 1 : dg;
    float dn = rsqrtf((float)d);
    float4 b = *(const float4*)(bias + q * 4);
    float o0 = 1.f / (1.f + __expf(-(a0 * dn + b.x))) + 1e-8f;
    float o1 = 1.f / (1.f + __expf(-(a1 * dn + b.y))) + 1e-8f;
    float o2 = 1.f / (1.f + __expf(-(a2 * dn + b.z))) + 1e-8f;
    float o3 = 1.f / (1.f + __expf(-(a3 * dn + b.w))) + 1e-8f;
    *(float4*)(out + (size_t)v * 16 + q * 4) = make_float4(o0, o1, o2, o3);
}

extern "C" void kernel_launch(void* const* d_in, const int* in_sizes, int n_in,
                              void* d_out, int out_size, void* d_ws, size_t ws_size,
                              hipStream_t stream) {
    const float* features = (const float*)d_in[0];
    const int*   src      = (const int*)d_in[1];
    const int*   dst      = (const int*)d_in[2];
    const float* W0       = (const float*)d_in[3];
    const float* b0       = (const float*)d_in[4];
    const float* W1       = (const float*)d_in[5];
    const float* b1       = (const float*)d_in[6];
    const float* W2       = (const float*)d_in[7];
    const float* b2       = (const float*)d_in[8];
    float* out = (float*)d_out;

    const int N = in_sizes[0] / 128;
    const int E = in_sizes[1];
    const int NB = (N + 127) >> 7;            // 782 buckets
    const int nblk = (E + CH - 1) / CH;       // 196 partition chunks

    char* ws = (char*)d_ws;
    size_t off = 0;
    auto alloc = [&](size_t bytes) -> char* {
        char* p = ws + off;
        off += (bytes + 255) / 256 * 256;
        return p;
    };
    int* pmat_d  = (int*)alloc((size_t)nblk * NB * 4);
    int* pmat_s  = (int*)alloc((size_t)nblk * NB * 4);
    int* omat_d  = (int*)alloc((size_t)nblk * NB * 4);
    int* omat_s  = (int*)alloc((size_t)nblk * NB * 4);
    int* bbase_d = (int*)alloc((size_t)(NB + 1) * 4);
    int* bbase_s = (int*)alloc((size_t)(NB + 1) * 4);
    unsigned int*  ebuf_d = (unsigned int*)alloc((size_t)E * 4);
    unsigned char* ebuf_s = (unsigned char*)alloc((size_t)E);
    int* csr     = (int*)alloc(((size_t)E + (size_t)NB * 512 + 512) * 4);   // padded CSR
    int* rowptr  = (int*)alloc((size_t)(N + 1) * 4);
    int* deg     = (int*)alloc((size_t)N * 4);
    float* srcn  = (float*)alloc((size_t)N * 4);
    unsigned short* Wt0 = (unsigned short*)alloc(128 * 128 * 2);
    unsigned short* Wt1 = (unsigned short*)alloc(128 * 128 * 2);
    unsigned short* Wt2 = (unsigned short*)alloc(16 * 128 * 2);
    unsigned short* B1 = (unsigned short*)alloc((size_t)N * 128 * 2);
    unsigned short* B2 = (unsigned short*)alloc((size_t)(N + 1) * 128 * 2);  // +1 zero pad row
    unsigned short* HW16 = (unsigned short*)alloc((size_t)(N + 1) * 16 * 2); // +1 zero pad row
    (void)ws_size; (void)n_in; (void)out_size;

    // graph build (no global data atomics)
    k_pcount<<<nblk, 256, 0, stream>>>(src, dst, pmat_d, pmat_s, E, NB);
    k_pscan<<<2, 1024, 0, stream>>>(pmat_d, pmat_s, bbase_d, bbase_s, omat_d, omat_s, B2, HW16, N, NB, nblk);
    k_pscatter<<<nblk, 256, 0, stream>>>(src, dst, omat_d, omat_s, ebuf_d, ebuf_s, E, NB);
    k_build<<<2 * NB + 136, 256, 0, stream>>>(ebuf_d, bbase_d, ebuf_s, bbase_s, csr, rowptr, deg, srcn,
                                              W0, W1, W2, Wt0, Wt1, Wt2, N, NB);

    int gb = (N + 255) / 256;                 // 391 GEMM blocks (4 waves x 64 rows)
    int anb = (N * 16 + 255) / 256;
    int a16b = (N * 4 + 255) / 256;

    // layer 0 (fp32 features, scaled by srcn during fragment load)
    k_gemm_mfma<8, 1><<<gb, 256, 0, stream>>>(nullptr, features, srcn, Wt0, B2, N);
    k_aggN<<<anb, 256, 0, stream>>>(B2, csr, rowptr, deg, srcn, b0, B1, N);
    // layer 1
    k_gemm_mfma<8, 0><<<gb, 256, 0, stream>>>(B1, nullptr, nullptr, Wt1, B2, N);
    k_aggN<<<anb, 256, 0, stream>>>(B2, csr, rowptr, deg, srcn, b1, B1, N);
    // layer 2: GEMM to 16-wide first, then 32B-row gather w/ bias+sigmoid
    k_gemm_mfma<1, 0><<<gb, 256, 0, stream>>>(B1, nullptr, nullptr, Wt2, HW16, N);
    k_agg16<<<a16b, 256, 0, stream>>>(HW16, csr, rowptr, deg, b2, out, N);
}